// Round 18
// baseline (213.122 us; speedup 1.0000x reference)
//
#include <hip/hip_runtime.h>
#include <hip/hip_bf16.h>

typedef unsigned short u16;
typedef __attribute__((ext_vector_type(4))) float f32x4;
typedef __attribute__((ext_vector_type(16))) float f32x16;
typedef __attribute__((ext_vector_type(8))) short s16x8;
typedef __attribute__((ext_vector_type(4))) unsigned short u16x4;

// ---------- helpers ----------
__device__ __forceinline__ u16 f2bf(float f) {
    union { float f; unsigned u; } v; v.f = f;
    unsigned r = v.u + 0x7fffu + ((v.u >> 16) & 1u);  // RNE (software)
    return (u16)(r >> 16);
}
__device__ __forceinline__ u16 f2bfh(float f) {   // hardware cvt via compiler
    __hip_bfloat16 h = __float2bfloat16(f);
    return *reinterpret_cast<u16*>(&h);
}
__device__ __forceinline__ float bf2f(u16 h) {
    union { unsigned u; float f; } v; v.u = ((unsigned)h) << 16;
    return v.f;
}
__device__ __forceinline__ float fexp2(float x) {
#if __has_builtin(__builtin_amdgcn_exp2f)
    return __builtin_amdgcn_exp2f(x);
#else
    return exp2f(x);
#endif
}
__device__ __forceinline__ void gload16(const void* g, void* lds_uniform) {
    __builtin_amdgcn_global_load_lds(
        (const __attribute__((address_space(1))) void*)g,
        (__attribute__((address_space(3))) void*)lds_uniform, 16, 0, 0);
}
__device__ __forceinline__ f32x4 mfma16(s16x8 a, s16x8 b, f32x4 c) {
    return __builtin_amdgcn_mfma_f32_16x16x32_bf16(a, b, c, 0, 0, 0);
}
__device__ __forceinline__ f32x16 mfma32(s16x8 a, s16x8 b, f32x16 c) {
    return __builtin_amdgcn_mfma_f32_32x32x16_bf16(a, b, c, 0, 0, 0);
}

// ---------- fused prep: cvt(q,k,v)->bf16 | weight transpose | mask packing ----------
// blocks [0,12288): convert; [12288,13312): wtrans; [13312,78848): packmask
__global__ void prep(const float4* __restrict__ q, const float4* __restrict__ k,
                     const float4* __restrict__ v, u16x4* __restrict__ qkv,
                     const float* __restrict__ Wq, const float* __restrict__ Wk,
                     const float* __restrict__ Wv, const float* __restrict__ Wo,
                     u16* __restrict__ WqT, u16* __restrict__ WkT,
                     u16* __restrict__ WvT, u16* __restrict__ WoT,
                     const int* __restrict__ mask, unsigned* __restrict__ bits) {
    __shared__ float tile[32][33];
    const int bid = blockIdx.x, tid = threadIdx.x;
    if (bid < 12288) {
        int i = bid * 256 + tid;               // 0 .. 3*2^20-1
        int sel = i >> 20, j = i & 0xFFFFF;
        const float4* in = (sel == 0) ? q : (sel == 1) ? k : v;
        float4 f = in[j];
        u16x4 o;
        o[0] = f2bf(f.x); o[1] = f2bf(f.y); o[2] = f2bf(f.z); o[3] = f2bf(f.w);
        qkv[i] = o;
    } else if (bid < 13312) {
        int idx = bid - 12288;
        int bz = idx >> 8, rem = idx & 255, by = rem >> 4, bx = rem & 15;
        const float* W; u16* T;
        switch (bz) {
            case 0: W = Wq; T = WqT; break;
            case 1: W = Wk; T = WkT; break;
            case 2: W = Wv; T = WvT; break;
            default: W = Wo; T = WoT; break;
        }
        const int tx = tid & 31, ty = tid >> 5;
        const int k0 = by * 32, n0 = bx * 32;
#pragma unroll
        for (int r = 0; r < 32; r += 8) tile[ty + r][tx] = W[(k0 + ty + r) * 512 + n0 + tx];
        __syncthreads();
#pragma unroll
        for (int r = 0; r < 32; r += 8) T[(n0 + ty + r) * 512 + k0 + tx] = f2bf(tile[tx][ty + r]);
    } else {
        int i = (bid - 13312) * 256 + tid;
        int m = mask[i];
        unsigned long long bal = __ballot(m != 0);
        if ((tid & 63) == 0) {
            uint2 w2; w2.x = (unsigned)bal; w2.y = (unsigned)(bal >> 32);
            *(uint2*)&bits[i >> 5] = w2;
        }
    }
}

// ---------- bf16 GEMM: C[m][n] = (sum_k A[m][k]*Bt[n][k] + bias) * scale ----------
// BN=64, BK=64, 4 waves as 2x2. BM in {64,128}. PROVEN r12/r13 compute.
// XCD-clustered tile mapping (T1; r17: -9.7us total on the three GEMMs).
template <int BM, int BIAS_ROW, int OUT_F32, int XSMALL>
__global__ __launch_bounds__(256, 4) void gemm_bt(
    const u16* __restrict__ A, const u16* __restrict__ Bt0, const u16* __restrict__ Bt1,
    const float* __restrict__ bias0, const float* __restrict__ bias1,
    void* __restrict__ Cout, int M, int N, int K, int ysplit,
    float scale0, float scale1) {
    constexpr int MR = BM / 32;
    const int bidl = blockIdx.x + blockIdx.y * gridDim.x;
    const int xcd = bidl & 7, slot = bidl >> 3;
    const int big = slot >> 3, small = slot & 7;
    int bx, by;
    if (XSMALL) { bx = small; by = xcd * ((int)gridDim.y >> 3) + big; }
    else        { by = small; bx = xcd * ((int)gridDim.x >> 3) + big; }
    const u16* Bt = (by < ysplit) ? Bt0 : Bt1;
    const float* bias = (by < ysplit) ? bias0 : bias1;
    const float scale = (by < ysplit) ? scale0 : scale1;
    __shared__ u16 As[BM * 64];
    __shared__ u16 Bs[64 * 64];
    const int t = threadIdx.x, l = t & 63, w = t >> 6;
    const int lr = l & 15, lg = l >> 4;
    const int m0 = by * BM, n0 = bx * 64;
    const int wr = w >> 1, wc = w & 1;
    f32x4 acc[MR][2] = {};
    const int tr = t >> 3, tc8 = (t & 7) * 8;

    for (int kk = 0; kk < K; kk += 64) {
        __syncthreads();
#pragma unroll
        for (int i = 0; i < MR; ++i)
            gload16(A + (m0 + i * 32 + tr) * K + kk + tc8, As + i * 2048 + w * 512);
#pragma unroll
        for (int i = 0; i < 2; ++i)
            gload16(Bt + (n0 + i * 32 + tr) * K + kk + tc8, Bs + i * 2048 + w * 512);
        __syncthreads();
        s16x8 af[MR][2], bfr[2][2];
#pragma unroll
        for (int m = 0; m < MR; ++m)
#pragma unroll
            for (int kh = 0; kh < 2; ++kh)
                af[m][kh] = *(const s16x8*)&As[(wr * (BM / 2) + m * 16 + lr) * 64 + kh * 32 + lg * 8];
#pragma unroll
        for (int n = 0; n < 2; ++n)
#pragma unroll
            for (int kh = 0; kh < 2; ++kh)
                bfr[n][kh] = *(const s16x8*)&Bs[(wc * 32 + n * 16 + lr) * 64 + kh * 32 + lg * 8];
#pragma unroll
        for (int m = 0; m < MR; ++m)
#pragma unroll
            for (int n = 0; n < 2; ++n)
#pragma unroll
                for (int kh = 0; kh < 2; ++kh)
                    acc[m][n] = mfma16(af[m][kh], bfr[n][kh], acc[m][n]);
    }

#pragma unroll
    for (int n = 0; n < 2; ++n) {
        const int cg = n0 + wc * 32 + n * 16 + lr;
        const float bcol = BIAS_ROW ? 0.f : bias[cg];
#pragma unroll
        for (int m = 0; m < MR; ++m) {
            const int rbase = m0 + wr * (BM / 2) + m * 16 + lg * 4;
#pragma unroll
            for (int j = 0; j < 4; ++j) {
                const int rg = rbase + j;
                float val = (acc[m][n][j] + (BIAS_ROW ? bias[rg] : bcol)) * scale;
                if (OUT_F32) ((float*)Cout)[(size_t)rg * N + cg] = val;
                else         ((u16*)Cout)[(size_t)rg * N + cg] = f2bf(val);
            }
        }
    }
}

// ---------- flash attention, KV-split z=2, XCD-clustered, ZERO-LDS ----------
// After r16's XCD clustering each XCD's K/V working set is 2 MB (L2-fit), so
// LDS staging was pure overhead (guide m169 pattern). K and V fragments are
// read DIRECTLY from global per-lane (16B contiguous each):
//   ka = Kp[(bS+ktb+kt_t*32+lq)*512 + h*64 + ds*16 + hi8]
//   va = Vt[(h*64+dt*32+lq)*8192  + bS+ktb+ks*16+hi8]
// — byte-identical values to what the LDS tiles delivered. The 4 ds-loads
// (resp. ks) cover each cache line fully and all 4 waves share tiles -> L1/L2
// hits. NO LDS, NO barriers; waves fully independent; 4 waves/SIMD resident.
__global__ __launch_bounds__(256, 4) void attn_fwd(
    const u16* __restrict__ Qp, const u16* __restrict__ Kp,
    const u16* __restrict__ Vt, const unsigned* __restrict__ mbits,
    u16* __restrict__ ppo, float* __restrict__ lws) {
    constexpr int S = 2048;
    const int bid = blockIdx.x;
    const int xcd = bid & 7, slot = bid >> 3;
    const int qt = slot & 15;
    const int combo = xcd * 8 + (slot >> 4);
    const int bh = combo & 31, z = combo >> 5;
    const int kbase = z << 10;                   // 0 or 1024
    const int b = bh >> 3, h = bh & 7;
    const int t = threadIdx.x, l = t & 63, w = t >> 6;
    const int lq = l & 31, hi = l >> 5;
    const int hi8 = hi * 8, hi4 = hi * 4;

    const int q0w = qt * 128 + w * 32;
    const int bS = b * S;

    // Q as PV-B-style fragments: lane holds Q[q=lq][d = ds*16 + hi8 + j]
    s16x8 qf[4];
#pragma unroll
    for (int ds = 0; ds < 4; ++ds)
        qf[ds] = *(const s16x8*)&Qp[(bS + q0w + lq) * 512 + h * 64 + ds * 16 + hi8];

    f32x16 po[2];
#pragma unroll
    for (int r = 0; r < 16; ++r) { po[0][r] = 0.f; po[1][r] = 0.f; }
    float lrun = 0.f;

    // per-lane global bases for direct K/V fragment loads
    const u16* Kbase = Kp + (size_t)(bS + kbase + lq) * 512 + h * 64 + hi8;
    const u16* Vbase = Vt + (size_t)(h * 64 + lq) * 8192 + bS + kbase + hi8;
    const int mrow = (bS + q0w + lq) * 64 + (kbase >> 5);

    for (int it = 0; it < 16; ++it) {
        const uint2 mwv = *(const uint2*)&mbits[mrow + (it << 1)];
        const int ktb = it * 64;

        // ---- QK^T + softmax + in-register P repack, per 32-kt tile ----
        s16x8 bq[4];
#pragma unroll
        for (int kt_t = 0; kt_t < 2; ++kt_t) {
            f32x16 sc;
#pragma unroll
            for (int r = 0; r < 16; ++r) sc[r] = 0.f;
            __builtin_amdgcn_s_setprio(1);
#pragma unroll
            for (int ds = 0; ds < 4; ++ds) {
                // K[kt = ktb + kt_t*32 + lq][d = ds*16 + hi8 ..+8]
                s16x8 ka = *(const s16x8*)&Kbase[(size_t)(ktb + kt_t * 32) * 512 + ds * 16];
                sc = mfma32(ka, qf[ds], sc);
            }
            __builtin_amdgcn_s_setprio(0);

            const unsigned w32s = (kt_t ? mwv.y : mwv.x) >> hi4;
            float p[16];
            float ps = 0.f;
#pragma unroll
            for (int r = 0; r < 16; ++r) {
                const unsigned bmask = 1u << ((r & 3) + 8 * (r >> 2));
                const float e = fexp2(sc[r]);
                p[r] = (w32s & bmask) ? e : 0.f;
                ps += p[r];
            }
            lrun += ps;

            // pack row-pairs to bf16; swap halves so each lane owns its 8-run
            unsigned pk[8];
#pragma unroll
            for (int i = 0; i < 8; ++i) {
                unsigned v;
                asm("v_cvt_pk_bf16_f32 %0, %1, %2"
                    : "=v"(v) : "v"(p[2 * i]), "v"(p[2 * i + 1]));
                pk[i] = v;
            }
            asm("v_permlane32_swap_b32 %0, %1" : "+v"(pk[0]), "+v"(pk[2]));
            asm("v_permlane32_swap_b32 %0, %1" : "+v"(pk[1]), "+v"(pk[3]));
            asm("v_permlane32_swap_b32 %0, %1" : "+v"(pk[4]), "+v"(pk[6]));
            asm("v_permlane32_swap_b32 %0, %1" : "+v"(pk[5]), "+v"(pk[7]));
            union BQ { unsigned u[4]; s16x8 v; } b0, b1;
            b0.u[0] = pk[0]; b0.u[1] = pk[1]; b0.u[2] = pk[2]; b0.u[3] = pk[3];
            b1.u[0] = pk[4]; b1.u[1] = pk[5]; b1.u[2] = pk[6]; b1.u[3] = pk[7];
            bq[kt_t * 2]     = b0.v;   // kt-slice [32*kt_t,      +16)
            bq[kt_t * 2 + 1] = b1.v;   // kt-slice [32*kt_t + 16, +16)
        }

        // ---- PV: out^T[d][q] += V^T-slice * P^T-slice ----
        __builtin_amdgcn_s_setprio(1);
#pragma unroll
        for (int dt = 0; dt < 2; ++dt)
#pragma unroll
            for (int ks = 0; ks < 4; ++ks) {
                // V^T[d = dt*32 + lq][kt = ktb + ks*16 + hi8 ..+8]
                s16x8 va = *(const s16x8*)&Vbase[(size_t)(dt * 32) * 8192 + ktb + ks * 16];
                po[dt] = mfma32(va, bq[ks], po[dt]);
            }
        __builtin_amdgcn_s_setprio(0);
    }

    // ---- epilogue: per-half normalized partial + lrun (combine merges) ----
    lrun += __shfl_xor(lrun, 32);
    const float inv = 1.f / lrun;
    u16* pp = ppo + (size_t)z * 4194304;
    const int orow = (bS + q0w + lq) * 512 + h * 64;
#pragma unroll
    for (int dt = 0; dt < 2; ++dt)
#pragma unroll
        for (int r = 0; r < 16; r += 2) {
            const int d = dt * 32 + (r & 3) + 8 * (r >> 2) + hi4;
            const unsigned lo = f2bfh(po[dt][r] * inv);
            const unsigned hh = f2bfh(po[dt][r + 1] * inv);
            *(unsigned*)&pp[orow + d] = lo | (hh << 16);
        }
    if (hi == 0) lws[z * 65536 + bh * 2048 + q0w + lq] = lrun;
}

// ---------- combine: AO = (oA*lA + oB*lB) / (lA+lB) ----------
__global__ __launch_bounds__(256) void combine(const u16* __restrict__ po,
                                               const float* __restrict__ lw,
                                               u16* __restrict__ AO) {
    const int i = (blockIdx.x * 256 + threadIdx.x) * 8;
    const int row = i >> 9, col = i & 511;
    const int lidx = ((row >> 11) * 8 + (col >> 6)) * 2048 + (row & 2047);
    const float la = lw[lidx], lb = lw[65536 + lidx];
    const float wa = la / (la + lb), wb = 1.f - wa;
    s16x8 a = *(const s16x8*)&po[i];
    s16x8 c = *(const s16x8*)&po[4194304 + i];
    s16x8 o;
#pragma unroll
    for (int j = 0; j < 8; ++j)
        o[j] = (short)f2bfh(bf2f((u16)a[j]) * wa + bf2f((u16)c[j]) * wb);
    *(s16x8*)&AO[i] = o;
}

// ---------- launcher ----------
extern "C" void kernel_launch(void* const* d_in, const int* in_sizes, int n_in,
                              void* d_out, int out_size, void* d_ws, size_t ws_size,
                              hipStream_t stream) {
    (void)in_sizes; (void)n_in; (void)out_size; (void)ws_size;
    const float* query = (const float*)d_in[0];
    const float* key   = (const float*)d_in[1];
    const float* value = (const float*)d_in[2];
    const int*   mask  = (const int*)d_in[3];
    const float* Wq = (const float*)d_in[4];
    const float* bq = (const float*)d_in[5];
    const float* Wk = (const float*)d_in[6];
    const float* bk = (const float*)d_in[7];
    const float* Wv = (const float*)d_in[8];
    const float* bv = (const float*)d_in[9];
    const float* Wo = (const float*)d_in[10];
    const float* bo = (const float*)d_in[11];

    char* ws = (char*)d_ws;
    const size_t MB = 1ull << 20;
    u16* qb  = (u16*)(ws);                       // 24 MB: qb|kb|vb contiguous
    u16* vb  = (u16*)(ws + 16 * MB);
    u16* WqT = (u16*)(ws + 24 * MB);
    u16* WkT = (u16*)(ws + 24 * MB + 512 * 1024);
    u16* WvT = (u16*)(ws + 25 * MB);
    u16* WoT = (u16*)(ws + 25 * MB + 512 * 1024);
    unsigned* mb = (unsigned*)(ws + 26 * MB);    // 2 MB
    u16* Qp = (u16*)(ws + 28 * MB);              // Qp|Kp contiguous 16 MB
    u16* Vt = (u16*)(ws + 44 * MB);              // [512][8192]
    u16* AO = (u16*)(ws + 52 * MB);              // end: 60 MB
    // attn-time scratch (qb/vb dead once projections finish; rewritten every call):
    u16* ppo = (u16*)(ws);                       // 2 x 4,194,304 u16 = 16.8 MB
    float* lws = (float*)(ws + 17 * MB);         // 2 x 65,536 f32 = 512 KB

    prep<<<78848, 256, 0, stream>>>((const float4*)query, (const float4*)key,
                                    (const float4*)value, (u16x4*)qb,
                                    Wq, Wk, Wv, Wo, WqT, WkT, WvT, WoT, mask, mb);

    // Q and K projections fused: rows 0..8191 -> Wq (pre-scaled by
    // 0.125*log2(e) for the exp2 softmax), rows 8192..16383 -> Wk
    gemm_bt<128, 0, 0, 1><<<dim3(8, 128), 256, 0, stream>>>(
        qb, WqT, WkT, bq, bk, Qp, 16384, 512, 512, 64, 0.18033688f, 1.0f);
    // V projection transposed: C[d][s] = (Wv^T)[d][:] . Xv[s][:] + bv[d] = Vproj^T
    gemm_bt<64, 1, 0, 0><<<dim3(128, 8), 256, 0, stream>>>(
        WvT, vb, vb, bv, bv, Vt, 512, 8192, 512, 999, 1.0f, 1.0f);

    attn_fwd<<<1024, 256, 0, stream>>>(Qp, Qp + 8192 * 512, Vt, mb, ppo, lws);
    combine<<<2048, 256, 0, stream>>>(ppo, lws, AO);

    // output projection -> fp32 d_out
    gemm_bt<64, 0, 1, 1><<<dim3(8, 128), 256, 0, stream>>>(
        AO, WoT, WoT, bo, bo, (float*)d_out, 8192, 512, 512, 999, 1.0f, 1.0f);
}

// Round 19
// 136.952 us; speedup vs baseline: 1.5562x; 1.5562x over previous
//
#include <hip/hip_runtime.h>
#include <hip/hip_bf16.h>

typedef unsigned short u16;
typedef __attribute__((ext_vector_type(4))) float f32x4;
typedef __attribute__((ext_vector_type(16))) float f32x16;
typedef __attribute__((ext_vector_type(8))) short s16x8;
typedef __attribute__((ext_vector_type(4))) unsigned short u16x4;

// ---------- helpers ----------
__device__ __forceinline__ u16 f2bf(float f) {
    union { float f; unsigned u; } v; v.f = f;
    unsigned r = v.u + 0x7fffu + ((v.u >> 16) & 1u);  // RNE (software)
    return (u16)(r >> 16);
}
__device__ __forceinline__ u16 f2bfh(float f) {   // hardware cvt via compiler
    __hip_bfloat16 h = __float2bfloat16(f);
    return *reinterpret_cast<u16*>(&h);
}
__device__ __forceinline__ float bf2f(u16 h) {
    union { unsigned u; float f; } v; v.u = ((unsigned)h) << 16;
    return v.f;
}
__device__ __forceinline__ float fexp2(float x) {
#if __has_builtin(__builtin_amdgcn_exp2f)
    return __builtin_amdgcn_exp2f(x);
#else
    return exp2f(x);
#endif
}
__device__ __forceinline__ void gload16(const void* g, void* lds_uniform) {
    __builtin_amdgcn_global_load_lds(
        (const __attribute__((address_space(1))) void*)g,
        (__attribute__((address_space(3))) void*)lds_uniform, 16, 0, 0);
}
__device__ __forceinline__ f32x4 mfma16(s16x8 a, s16x8 b, f32x4 c) {
    return __builtin_amdgcn_mfma_f32_16x16x32_bf16(a, b, c, 0, 0, 0);
}
__device__ __forceinline__ f32x16 mfma32(s16x8 a, s16x8 b, f32x16 c) {
    return __builtin_amdgcn_mfma_f32_32x32x16_bf16(a, b, c, 0, 0, 0);
}

// ---------- fused prep: cvt(q,k,v)->bf16 | weight transpose | mask packing ----------
// blocks [0,12288): convert; [12288,13312): wtrans; [13312,78848): packmask
__global__ void prep(const float4* __restrict__ q, const float4* __restrict__ k,
                     const float4* __restrict__ v, u16x4* __restrict__ qkv,
                     const float* __restrict__ Wq, const float* __restrict__ Wk,
                     const float* __restrict__ Wv, const float* __restrict__ Wo,
                     u16* __restrict__ WqT, u16* __restrict__ WkT,
                     u16* __restrict__ WvT, u16* __restrict__ WoT,
                     const int* __restrict__ mask, unsigned* __restrict__ bits) {
    __shared__ float tile[32][33];
    const int bid = blockIdx.x, tid = threadIdx.x;
    if (bid < 12288) {
        int i = bid * 256 + tid;               // 0 .. 3*2^20-1
        int sel = i >> 20, j = i & 0xFFFFF;
        const float4* in = (sel == 0) ? q : (sel == 1) ? k : v;
        float4 f = in[j];
        u16x4 o;
        o[0] = f2bf(f.x); o[1] = f2bf(f.y); o[2] = f2bf(f.z); o[3] = f2bf(f.w);
        qkv[i] = o;
    } else if (bid < 13312) {
        int idx = bid - 12288;
        int bz = idx >> 8, rem = idx & 255, by = rem >> 4, bx = rem & 15;
        const float* W; u16* T;
        switch (bz) {
            case 0: W = Wq; T = WqT; break;
            case 1: W = Wk; T = WkT; break;
            case 2: W = Wv; T = WvT; break;
            default: W = Wo; T = WoT; break;
        }
        const int tx = tid & 31, ty = tid >> 5;
        const int k0 = by * 32, n0 = bx * 32;
#pragma unroll
        for (int r = 0; r < 32; r += 8) tile[ty + r][tx] = W[(k0 + ty + r) * 512 + n0 + tx];
        __syncthreads();
#pragma unroll
        for (int r = 0; r < 32; r += 8) T[(n0 + ty + r) * 512 + k0 + tx] = f2bf(tile[tx][ty + r]);
    } else {
        int i = (bid - 13312) * 256 + tid;
        int m = mask[i];
        unsigned long long bal = __ballot(m != 0);
        if ((tid & 63) == 0) {
            uint2 w2; w2.x = (unsigned)bal; w2.y = (unsigned)(bal >> 32);
            *(uint2*)&bits[i >> 5] = w2;
        }
    }
}

// ---------- bf16 GEMM: C[m][n] = (sum_k A[m][k]*Bt[n][k] + bias) * scale ----------
// BN=64, BK=64, 4 waves as 2x2. BM in {64,128}. PROVEN r12/r13 compute.
// XCD-clustered tile mapping (T1; r17: -9.7us total on the three GEMMs).
template <int BM, int BIAS_ROW, int OUT_F32, int XSMALL>
__global__ __launch_bounds__(256, 4) void gemm_bt(
    const u16* __restrict__ A, const u16* __restrict__ Bt0, const u16* __restrict__ Bt1,
    const float* __restrict__ bias0, const float* __restrict__ bias1,
    void* __restrict__ Cout, int M, int N, int K, int ysplit,
    float scale0, float scale1) {
    constexpr int MR = BM / 32;
    const int bidl = blockIdx.x + blockIdx.y * gridDim.x;
    const int xcd = bidl & 7, slot = bidl >> 3;
    const int big = slot >> 3, small = slot & 7;
    int bx, by;
    if (XSMALL) { bx = small; by = xcd * ((int)gridDim.y >> 3) + big; }
    else        { by = small; bx = xcd * ((int)gridDim.x >> 3) + big; }
    const u16* Bt = (by < ysplit) ? Bt0 : Bt1;
    const float* bias = (by < ysplit) ? bias0 : bias1;
    const float scale = (by < ysplit) ? scale0 : scale1;
    __shared__ u16 As[BM * 64];
    __shared__ u16 Bs[64 * 64];
    const int t = threadIdx.x, l = t & 63, w = t >> 6;
    const int lr = l & 15, lg = l >> 4;
    const int m0 = by * BM, n0 = bx * 64;
    const int wr = w >> 1, wc = w & 1;
    f32x4 acc[MR][2] = {};
    const int tr = t >> 3, tc8 = (t & 7) * 8;

    for (int kk = 0; kk < K; kk += 64) {
        __syncthreads();
#pragma unroll
        for (int i = 0; i < MR; ++i)
            gload16(A + (m0 + i * 32 + tr) * K + kk + tc8, As + i * 2048 + w * 512);
#pragma unroll
        for (int i = 0; i < 2; ++i)
            gload16(Bt + (n0 + i * 32 + tr) * K + kk + tc8, Bs + i * 2048 + w * 512);
        __syncthreads();
        s16x8 af[MR][2], bfr[2][2];
#pragma unroll
        for (int m = 0; m < MR; ++m)
#pragma unroll
            for (int kh = 0; kh < 2; ++kh)
                af[m][kh] = *(const s16x8*)&As[(wr * (BM / 2) + m * 16 + lr) * 64 + kh * 32 + lg * 8];
#pragma unroll
        for (int n = 0; n < 2; ++n)
#pragma unroll
            for (int kh = 0; kh < 2; ++kh)
                bfr[n][kh] = *(const s16x8*)&Bs[(wc * 32 + n * 16 + lr) * 64 + kh * 32 + lg * 8];
#pragma unroll
        for (int m = 0; m < MR; ++m)
#pragma unroll
            for (int n = 0; n < 2; ++n)
#pragma unroll
                for (int kh = 0; kh < 2; ++kh)
                    acc[m][n] = mfma16(af[m][kh], bfr[n][kh], acc[m][n]);
    }

#pragma unroll
    for (int n = 0; n < 2; ++n) {
        const int cg = n0 + wc * 32 + n * 16 + lr;
        const float bcol = BIAS_ROW ? 0.f : bias[cg];
#pragma unroll
        for (int m = 0; m < MR; ++m) {
            const int rbase = m0 + wr * (BM / 2) + m * 16 + lg * 4;
#pragma unroll
            for (int j = 0; j < 4; ++j) {
                const int rg = rbase + j;
                float val = (acc[m][n][j] + (BIAS_ROW ? bias[rg] : bcol)) * scale;
                if (OUT_F32) ((float*)Cout)[(size_t)rg * N + cg] = val;
                else         ((u16*)Cout)[(size_t)rg * N + cg] = f2bf(val);
            }
        }
    }
}

// ---------- flash attention, KV-split z=2, XCD-clustered block mapping ----------
// 1024 blocks (1D). Decode: xcd=bid&7, slot=bid>>3, qt=slot&15,
// combo=xcd*8+(slot>>4), bh=combo&31, z=combo>>5 — bijective; K/V panel per
// (bh,z) stays on one XCD's L2 (r16: FETCH 70.8->17.4 MB). LDS staging via
// global_load_lds is ESSENTIAL (r18: direct per-lane global K/V reads =
// 32 lines/instr uncoalesced -> 2.2x regression). Mask test uses the
// hi4-pre-shifted word + literal bit masks, selecting on the exp2 result.
__global__ __launch_bounds__(256, 4) void attn_fwd(
    const u16* __restrict__ Qp, const u16* __restrict__ Kp,
    const u16* __restrict__ Vt, const unsigned* __restrict__ mbits,
    u16* __restrict__ ppo, float* __restrict__ lws) {
    constexpr int S = 2048;
    const int bid = blockIdx.x;
    const int xcd = bid & 7, slot = bid >> 3;
    const int qt = slot & 15;
    const int combo = xcd * 8 + (slot >> 4);
    const int bh = combo & 31, z = combo >> 5;
    const int kbase = z << 10;                   // 0 or 1024
    const int b = bh >> 3, h = bh & 7;
    const int t = threadIdx.x, l = t & 63, w = t >> 6;
    const int lq = l & 31, hi = l >> 5;
    const int hi8 = hi * 8, hi4 = hi * 4;

    __shared__ u16 Ks[2][64 * 64];   // [buf][kt][d], XOR-swizzled chunks
    __shared__ u16 Vs[2][64 * 64];   // [buf][d][kt], XOR-swizzled chunks

    const int q0w = qt * 128 + w * 32;
    const int bS = b * S;

    // Q as PV-B-style fragments: lane holds Q[q=lq][d = ds*16 + hi8 + j]
    s16x8 qf[4];
#pragma unroll
    for (int ds = 0; ds < 4; ++ds)
        qf[ds] = *(const s16x8*)&Qp[(bS + q0w + lq) * 512 + h * 64 + ds * 16 + hi8];

    f32x16 po[2];
#pragma unroll
    for (int r = 0; r < 16; ++r) { po[0][r] = 0.f; po[1][r] = 0.f; }
    float lrun = 0.f;

    // staging chunk assignment (inverse-XOR on global source -> swizzled LDS)
    const int kc0 = t, kc1 = 256 + t;
    const int krow0 = kc0 >> 3, kcol0 = ((kc0 & 7) ^ (krow0 & 7)) * 8;
    const int krow1 = kc1 >> 3, kcol1 = ((kc1 & 7) ^ (krow1 & 7)) * 8;

#define STAGE(nb, kt0)                                                              \
    do {                                                                            \
        gload16(&Kp[(bS + (kt0) + krow0) * 512 + h * 64 + kcol0], &Ks[nb][w * 512]);\
        gload16(&Kp[(bS + (kt0) + krow1) * 512 + h * 64 + kcol1], &Ks[nb][2048 + w * 512]);\
        gload16(&Vt[(h * 64 + krow0) * (4 * S) + bS + (kt0) + kcol0], &Vs[nb][w * 512]);\
        gload16(&Vt[(h * 64 + krow1) * (4 * S) + bS + (kt0) + kcol1], &Vs[nb][2048 + w * 512]);\
    } while (0)

    const int mrow = (bS + q0w + lq) * 64 + (kbase >> 5);
    STAGE(0, kbase);
    uint2 mwv = *(const uint2*)&mbits[mrow];
    uint2 mwn = mwv;

    for (int it = 0; it < 16; ++it) {
        const int cur = it & 1;
        // single barrier/iter: implicit vmcnt(0) drains stage(it) and fences
        // buf reuse across the double buffer
        __syncthreads();
        if (it + 1 < 16) {
            STAGE(cur ^ 1, kbase + (it + 1) * 64);
            mwn = *(const uint2*)&mbits[mrow + ((it + 1) << 1)];
        }
        const u16* Kc = Ks[cur];
        const u16* Vc = Vs[cur];

        // ---- QK^T + softmax + in-register P repack, per 32-kt tile ----
        s16x8 bq[4];
#pragma unroll
        for (int kt_t = 0; kt_t < 2; ++kt_t) {
            f32x16 sc;
#pragma unroll
            for (int r = 0; r < 16; ++r) sc[r] = 0.f;
            __builtin_amdgcn_s_setprio(1);
#pragma unroll
            for (int ds = 0; ds < 4; ++ds) {
                const int row = kt_t * 32 + lq;
                const int byte = (row * 128 + ds * 32 + hi * 16) ^ ((row & 7) << 4);
                s16x8 ka = *(const s16x8*)((const char*)Kc + byte);
                sc = mfma32(ka, qf[ds], sc);
            }
            __builtin_amdgcn_s_setprio(0);

            const unsigned w32s = (kt_t ? mwv.y : mwv.x) >> hi4;
            float p[16];
            float ps = 0.f;
#pragma unroll
            for (int r = 0; r < 16; ++r) {
                const unsigned bmask = 1u << ((r & 3) + 8 * (r >> 2));
                const float e = fexp2(sc[r]);
                p[r] = (w32s & bmask) ? e : 0.f;
                ps += p[r];
            }
            lrun += ps;

            // pack row-pairs to bf16; swap halves so each lane owns its 8-run
            unsigned pk[8];
#pragma unroll
            for (int i = 0; i < 8; ++i) {
                unsigned v;
                asm("v_cvt_pk_bf16_f32 %0, %1, %2"
                    : "=v"(v) : "v"(p[2 * i]), "v"(p[2 * i + 1]));
                pk[i] = v;
            }
            asm("v_permlane32_swap_b32 %0, %1" : "+v"(pk[0]), "+v"(pk[2]));
            asm("v_permlane32_swap_b32 %0, %1" : "+v"(pk[1]), "+v"(pk[3]));
            asm("v_permlane32_swap_b32 %0, %1" : "+v"(pk[4]), "+v"(pk[6]));
            asm("v_permlane32_swap_b32 %0, %1" : "+v"(pk[5]), "+v"(pk[7]));
            union BQ { unsigned u[4]; s16x8 v; } b0, b1;
            b0.u[0] = pk[0]; b0.u[1] = pk[1]; b0.u[2] = pk[2]; b0.u[3] = pk[3];
            b1.u[0] = pk[4]; b1.u[1] = pk[5]; b1.u[2] = pk[6]; b1.u[3] = pk[7];
            bq[kt_t * 2]     = b0.v;   // kt-slice [32*kt_t,      +16)
            bq[kt_t * 2 + 1] = b1.v;   // kt-slice [32*kt_t + 16, +16)
        }

        // ---- PV: out^T[d][q] += V^T-slice * P^T-slice ----
        __builtin_amdgcn_s_setprio(1);
#pragma unroll
        for (int dt = 0; dt < 2; ++dt)
#pragma unroll
            for (int ks = 0; ks < 4; ++ks) {
                const int row = dt * 32 + lq;
                const int byte = (row * 128 + ks * 32 + hi * 16) ^ ((row & 7) << 4);
                s16x8 va = *(const s16x8*)((const char*)Vc + byte);
                po[dt] = mfma32(va, bq[ks], po[dt]);
            }
        __builtin_amdgcn_s_setprio(0);

        mwv = mwn;
    }
#undef STAGE

    // ---- epilogue: per-half normalized partial + lrun (combine merges) ----
    lrun += __shfl_xor(lrun, 32);
    const float inv = 1.f / lrun;
    u16* pp = ppo + (size_t)z * 4194304;
    const int orow = (bS + q0w + lq) * 512 + h * 64;
#pragma unroll
    for (int dt = 0; dt < 2; ++dt)
#pragma unroll
        for (int r = 0; r < 16; r += 2) {
            const int d = dt * 32 + (r & 3) + 8 * (r >> 2) + hi4;
            const unsigned lo = f2bfh(po[dt][r] * inv);
            const unsigned hh = f2bfh(po[dt][r + 1] * inv);
            *(unsigned*)&pp[orow + d] = lo | (hh << 16);
        }
    if (hi == 0) lws[z * 65536 + bh * 2048 + q0w + lq] = lrun;
}

// ---------- combine: AO = (oA*lA + oB*lB) / (lA+lB) ----------
__global__ __launch_bounds__(256) void combine(const u16* __restrict__ po,
                                               const float* __restrict__ lw,
                                               u16* __restrict__ AO) {
    const int i = (blockIdx.x * 256 + threadIdx.x) * 8;
    const int row = i >> 9, col = i & 511;
    const int lidx = ((row >> 11) * 8 + (col >> 6)) * 2048 + (row & 2047);
    const float la = lw[lidx], lb = lw[65536 + lidx];
    const float wa = la / (la + lb), wb = 1.f - wa;
    s16x8 a = *(const s16x8*)&po[i];
    s16x8 c = *(const s16x8*)&po[4194304 + i];
    s16x8 o;
#pragma unroll
    for (int j = 0; j < 8; ++j)
        o[j] = (short)f2bfh(bf2f((u16)a[j]) * wa + bf2f((u16)c[j]) * wb);
    *(s16x8*)&AO[i] = o;
}

// ---------- launcher ----------
extern "C" void kernel_launch(void* const* d_in, const int* in_sizes, int n_in,
                              void* d_out, int out_size, void* d_ws, size_t ws_size,
                              hipStream_t stream) {
    (void)in_sizes; (void)n_in; (void)out_size; (void)ws_size;
    const float* query = (const float*)d_in[0];
    const float* key   = (const float*)d_in[1];
    const float* value = (const float*)d_in[2];
    const int*   mask  = (const int*)d_in[3];
    const float* Wq = (const float*)d_in[4];
    const float* bq = (const float*)d_in[5];
    const float* Wk = (const float*)d_in[6];
    const float* bk = (const float*)d_in[7];
    const float* Wv = (const float*)d_in[8];
    const float* bv = (const float*)d_in[9];
    const float* Wo = (const float*)d_in[10];
    const float* bo = (const float*)d_in[11];

    char* ws = (char*)d_ws;
    const size_t MB = 1ull << 20;
    u16* qb  = (u16*)(ws);                       // 24 MB: qb|kb|vb contiguous
    u16* vb  = (u16*)(ws + 16 * MB);
    u16* WqT = (u16*)(ws + 24 * MB);
    u16* WkT = (u16*)(ws + 24 * MB + 512 * 1024);
    u16* WvT = (u16*)(ws + 25 * MB);
    u16* WoT = (u16*)(ws + 25 * MB + 512 * 1024);
    unsigned* mb = (unsigned*)(ws + 26 * MB);    // 2 MB
    u16* Qp = (u16*)(ws + 28 * MB);              // Qp|Kp contiguous 16 MB
    u16* Vt = (u16*)(ws + 44 * MB);              // [512][8192]
    u16* AO = (u16*)(ws + 52 * MB);              // end: 60 MB
    // attn-time scratch (qb/vb dead once projections finish; rewritten every call):
    u16* ppo = (u16*)(ws);                       // 2 x 4,194,304 u16 = 16.8 MB
    float* lws = (float*)(ws + 17 * MB);         // 2 x 65,536 f32 = 512 KB

    prep<<<78848, 256, 0, stream>>>((const float4*)query, (const float4*)key,
                                    (const float4*)value, (u16x4*)qb,
                                    Wq, Wk, Wv, Wo, WqT, WkT, WvT, WoT, mask, mb);

    // Q and K projections fused: rows 0..8191 -> Wq (pre-scaled by
    // 0.125*log2(e) for the exp2 softmax), rows 8192..16383 -> Wk
    gemm_bt<128, 0, 0, 1><<<dim3(8, 128), 256, 0, stream>>>(
        qb, WqT, WkT, bq, bk, Qp, 16384, 512, 512, 64, 0.18033688f, 1.0f);
    // V projection transposed: C[d][s] = (Wv^T)[d][:] . Xv[s][:] + bv[d] = Vproj^T
    gemm_bt<64, 1, 0, 0><<<dim3(128, 8), 256, 0, stream>>>(
        WvT, vb, vb, bv, bv, Vt, 512, 8192, 512, 999, 1.0f, 1.0f);

    attn_fwd<<<1024, 256, 0, stream>>>(Qp, Qp + 8192 * 512, Vt, mb, ppo, lws);
    combine<<<2048, 256, 0, stream>>>(ppo, lws, AO);

    // output projection -> fp32 d_out
    gemm_bt<64, 0, 1, 1><<<dim3(8, 128), 256, 0, stream>>>(
        AO, WoT, WoT, bo, bo, (float*)d_out, 8192, 512, 512, 999, 1.0f, 1.0f);
}